// Round 1
// baseline (1201.682 us; speedup 1.0000x reference)
//
#include <hip/hip_runtime.h>
#include <stdint.h>

// ===== Problem constants (LinearQ4_0: x[4,2048,4096] fp16 -> fp32, W q4_0 [11008,4096]) =====
#define IN_F   4096
#define OUT_F  11008
#define M_ROWS 8192   // 4 * 2048

// Assumptions (from harness contract + npz-size evidence):
//   d_in[0] = x        : const float* (fp16 promoted to fp32), 33,554,432 elems
//   d_in[1] = linear_w : const int*   (int8 packed byte sign-extended to int32), 22,544,384 elems
//   d_in[2] = linear_s : const float* (fp16 scale promoted to fp32), 704,512 elems
//   d_out   = float*   (fp16 output promoted to fp32), 90,177,536 elems
// d_ws layout: [0, 90177536) bf16 dequantized W ; [90177536, +67108864) bf16 x. Total 157.3 MB.

typedef __attribute__((ext_vector_type(4))) float  f32x4;
typedef __attribute__((ext_vector_type(4))) int    int4v;
typedef __attribute__((ext_vector_type(8))) unsigned short ushort8;
typedef __bf16 bf16x8 __attribute__((ext_vector_type(8)));

__device__ __forceinline__ unsigned short f2bf(float f) {
  // round-to-nearest-even fp32 -> bf16
  unsigned int u = __builtin_bit_cast(unsigned int, f);
  u += 0x7fffu + ((u >> 16) & 1u);
  return (unsigned short)(u >> 16);
}

// ---- kernel 1: dequantize q4_0 -> bf16 W[OUT_F][IN_F] ----
__global__ __launch_bounds__(256) void dequant_q40(const int* __restrict__ w,
                                                   const float* __restrict__ sc,
                                                   unsigned short* __restrict__ wb) {
  const int total8 = (OUT_F * IN_F) / 8;  // 5,636,096
  for (int t = blockIdx.x * blockDim.x + threadIdx.x; t < total8;
       t += gridDim.x * blockDim.x) {
    const int f0  = t * 8;             // flat weight index of first of 8 outputs
    const int p   = f0 >> 7;           // packed row (covers groups 2p, 2p+1)
    const int nib = (f0 >> 6) & 1;     // 0 = MSB nibble, 1 = LSB nibble
    const int j0  = f0 & 63;           // within-group column
    const float scale = sc[f0 >> 6];   // per-group scale
    const int* src = w + p * 64 + j0;
    const int4v b0 = *reinterpret_cast<const int4v*>(src);
    const int4v b1 = *reinterpret_cast<const int4v*>(src + 4);
    ushort8 r;
#pragma unroll
    for (int e = 0; e < 4; ++e) {
      const int v0 = b0[e], v1 = b1[e];
      const int q0 = nib ? ((v0 << 28) >> 28) : (v0 >> 4);
      const int q1 = nib ? ((v1 << 28) >> 28) : (v1 >> 4);
      r[e]     = f2bf((float)q0 * scale);
      r[4 + e] = f2bf((float)q1 * scale);
    }
    *reinterpret_cast<ushort8*>(wb + f0) = r;
  }
}

// ---- kernel 2: x fp32 -> bf16 ----
__global__ __launch_bounds__(256) void cvt_x(const float* __restrict__ x,
                                             unsigned short* __restrict__ xb) {
  const int total8 = (M_ROWS * IN_F) / 8;  // 4,194,304
  for (int t = blockIdx.x * blockDim.x + threadIdx.x; t < total8;
       t += gridDim.x * blockDim.x) {
    const f32x4 a0 = *reinterpret_cast<const f32x4*>(x + t * 8);
    const f32x4 a1 = *reinterpret_cast<const f32x4*>(x + t * 8 + 4);
    ushort8 r;
#pragma unroll
    for (int e = 0; e < 4; ++e) {
      r[e]     = f2bf(a0[e]);
      r[4 + e] = f2bf(a1[e]);
    }
    *reinterpret_cast<ushort8*>(xb + t * 8) = r;
  }
}

// ---- async global -> LDS, 16 B per lane ----
__device__ __forceinline__ void gld16(const void* g, void* l) {
  __builtin_amdgcn_global_load_lds(
      (const __attribute__((address_space(1))) unsigned int*)(uintptr_t)g,
      (__attribute__((address_space(3))) unsigned int*)(unsigned int)(uintptr_t)l,
      16, 0, 0);
}

// ---- kernel 3: C[M][N] = A[M][K] * B[N][K]^T  (m97 structure: 128x128 tile, BK=32) ----
__global__ __launch_bounds__(256) void gemm_bt(const unsigned short* __restrict__ A,
                                               const unsigned short* __restrict__ B,
                                               float* __restrict__ C) {
  __shared__ __align__(16) unsigned short lA[128 * 32];  // 8 KB
  __shared__ __align__(16) unsigned short lB[128 * 32];  // 8 KB

  const int NT  = OUT_F / 128;              // 86
  const int nwg = (M_ROWS / 128) * NT;      // 5504 (% 8 == 0 -> simple bijective swizzle)
  const int cpx = nwg >> 3;
  const int bid = blockIdx.x;
  const int swz = (bid & 7) * cpx + (bid >> 3);  // XCD-contiguous chunks
  const int mt  = swz / NT;
  const int nt  = swz - mt * NT;
  const int m0  = mt * 128, n0 = nt * 128;

  const int tid  = threadIdx.x;
  const int lane = tid & 63;
  const int wid  = tid >> 6;      // 4 waves: 2x2 of 64x64 output
  const int wr   = wid >> 1, wc = wid & 1;

  // staging: chunk u = q*256 + tid ; row = u>>2 ; col-block = (u&3)*8
  const unsigned short* aP0 = A + (size_t)(m0 + (tid >> 2)) * IN_F + (tid & 3) * 8;
  const unsigned short* aP1 = aP0 + (size_t)64 * IN_F;
  const unsigned short* bP0 = B + (size_t)(n0 + (tid >> 2)) * IN_F + (tid & 3) * 8;
  const unsigned short* bP1 = bP0 + (size_t)64 * IN_F;
  unsigned short* lA0 = &lA[tid * 8];
  unsigned short* lA1 = &lA[(256 + tid) * 8];
  unsigned short* lB0 = &lB[tid * 8];
  unsigned short* lB1 = &lB[(256 + tid) * 8];

  const int fr = lane & 15;         // fragment row
  const int kq = (lane >> 4) * 8;   // k sub-block (8 contiguous bf16)

  f32x4 acc[4][4] = {};

  for (int kk = 0; kk < IN_F; kk += 32) {
    gld16(aP0 + kk, lA0);
    gld16(aP1 + kk, lA1);
    gld16(bP0 + kk, lB0);
    gld16(bP1 + kk, lB1);
    __syncthreads();  // drains vmcnt -> LDS tiles ready

    bf16x8 af[4], bg[4];
#pragma unroll
    for (int m = 0; m < 4; ++m)
      af[m] = *reinterpret_cast<const bf16x8*>(&lA[(wr * 64 + m * 16 + fr) * 32 + kq]);
#pragma unroll
    for (int n = 0; n < 4; ++n)
      bg[n] = *reinterpret_cast<const bf16x8*>(&lB[(wc * 64 + n * 16 + fr) * 32 + kq]);

#pragma unroll
    for (int m = 0; m < 4; ++m)
#pragma unroll
      for (int n = 0; n < 4; ++n)
        acc[m][n] = __builtin_amdgcn_mfma_f32_16x16x32_bf16(af[m], bg[n], acc[m][n], 0, 0, 0);

    __syncthreads();  // protect LDS before next-tile overwrite
  }

  // C/D layout (m89 verified): col = lane&15, row = (lane>>4)*4 + reg
  const int col  = n0 + wc * 64 + fr;
  const int row0 = m0 + wr * 64 + (lane >> 4) * 4;
#pragma unroll
  for (int m = 0; m < 4; ++m) {
#pragma unroll
    for (int n = 0; n < 4; ++n) {
      float* cp = C + (size_t)(row0 + m * 16) * OUT_F + (col + n * 16);
#pragma unroll
      for (int r = 0; r < 4; ++r) cp[(size_t)r * OUT_F] = acc[m][n][r];
    }
  }
}

extern "C" void kernel_launch(void* const* d_in, const int* in_sizes, int n_in,
                              void* d_out, int out_size, void* d_ws, size_t ws_size,
                              hipStream_t stream) {
  const float* x = (const float*)d_in[0];
  const int*   w = (const int*)d_in[1];
  const float* s = (const float*)d_in[2];
  float*     out = (float*)d_out;

  unsigned short* wb = (unsigned short*)d_ws;             // bf16 W  [OUT_F][IN_F]
  unsigned short* xb = wb + (size_t)OUT_F * IN_F;         // bf16 x  [M_ROWS][IN_F]

  dequant_q40<<<dim3(2048), dim3(256), 0, stream>>>(w, s, wb);
  cvt_x<<<dim3(2048), dim3(256), 0, stream>>>(x, xb);
  gemm_bt<<<dim3((M_ROWS / 128) * (OUT_F / 128)), dim3(256), 0, stream>>>(xb, wb, out);
}

// Round 2
// 755.045 us; speedup vs baseline: 1.5915x; 1.5915x over previous
//
#include <hip/hip_runtime.h>
#include <stdint.h>

// ===== LinearQ4_0: out[8192,11008] = x[8192,4096] * W^T, W q4_0 packed =====
#define IN_F   4096
#define OUT_F  11008
#define M_ROWS 8192
#define BM 256
#define BN 256
#define BK 64
#define NTILE_K (IN_F / BK)   // 64

typedef __attribute__((ext_vector_type(4))) float  f32x4;
typedef __attribute__((ext_vector_type(4))) int    int4v;
typedef __attribute__((ext_vector_type(8))) unsigned short ushort8;
typedef __bf16 bf16x8 __attribute__((ext_vector_type(8)));

__device__ __forceinline__ unsigned short f2bf(float f) {
  unsigned int u = __builtin_bit_cast(unsigned int, f);
  u += 0x7fffu + ((u >> 16) & 1u);
  return (unsigned short)(u >> 16);
}

// ---- kernel 1: dequantize q4_0 -> bf16 W[OUT_F][IN_F] ----
__global__ __launch_bounds__(256) void dequant_q40(const int* __restrict__ w,
                                                   const float* __restrict__ sc,
                                                   unsigned short* __restrict__ wb) {
  const int total8 = (OUT_F * IN_F) / 8;
  for (int t = blockIdx.x * blockDim.x + threadIdx.x; t < total8;
       t += gridDim.x * blockDim.x) {
    const int f0  = t * 8;
    const int p   = f0 >> 7;
    const int nib = (f0 >> 6) & 1;
    const int j0  = f0 & 63;
    const float scale = sc[f0 >> 6];
    const int* src = w + p * 64 + j0;
    const int4v b0 = *reinterpret_cast<const int4v*>(src);
    const int4v b1 = *reinterpret_cast<const int4v*>(src + 4);
    ushort8 r;
#pragma unroll
    for (int e = 0; e < 4; ++e) {
      const int v0 = b0[e], v1 = b1[e];
      const int q0 = nib ? ((v0 << 28) >> 28) : (v0 >> 4);
      const int q1 = nib ? ((v1 << 28) >> 28) : (v1 >> 4);
      r[e]     = f2bf((float)q0 * scale);
      r[4 + e] = f2bf((float)q1 * scale);
    }
    *reinterpret_cast<ushort8*>(wb + f0) = r;
  }
}

// ---- kernel 2: x fp32 -> bf16 ----
__global__ __launch_bounds__(256) void cvt_x(const float* __restrict__ x,
                                             unsigned short* __restrict__ xb) {
  const int total8 = (M_ROWS * IN_F) / 8;
  for (int t = blockIdx.x * blockDim.x + threadIdx.x; t < total8;
       t += gridDim.x * blockDim.x) {
    const f32x4 a0 = *reinterpret_cast<const f32x4*>(x + t * 8);
    const f32x4 a1 = *reinterpret_cast<const f32x4*>(x + t * 8 + 4);
    ushort8 r;
#pragma unroll
    for (int e = 0; e < 4; ++e) {
      r[e]     = f2bf(a0[e]);
      r[4 + e] = f2bf(a1[e]);
    }
    *reinterpret_cast<ushort8*>(xb + t * 8) = r;
  }
}

// ---- async global -> LDS, 16 B per lane ----
__device__ __forceinline__ void gld16(const void* g, void* l) {
  __builtin_amdgcn_global_load_lds(
      (const __attribute__((address_space(1))) unsigned int*)(uintptr_t)g,
      (__attribute__((address_space(3))) unsigned int*)(unsigned int)(uintptr_t)l,
      16, 0, 0);
}

#define BAR() do { asm volatile("" ::: "memory"); __builtin_amdgcn_s_barrier(); \
                   asm volatile("" ::: "memory"); } while (0)

// ---- kernel 3: 256x256 tile, BK=64, 8 waves, 4-phase/K-tile counted-vmcnt schedule ----
// LDS 128 KB: buf p at p*32768 ushorts: A[256][64] then B[256][64], XOR-swizzled
// (phys 16B-chunk = logical_chunk ^ (row&7); involution; gld_lds dest stays linear,
//  global SOURCE is inverse-swizzled; ds_read applies the same XOR).
__global__ __launch_bounds__(512, 2) void gemm_bt(const unsigned short* __restrict__ A,
                                                  const unsigned short* __restrict__ B,
                                                  float* __restrict__ C) {
  __shared__ __align__(16) unsigned short lds[65536];  // 128 KB

  const int NT  = OUT_F / BN;              // 43
  const int nwg = (M_ROWS / BM) * NT;      // 1376, %8==0
  const int cpx = nwg >> 3;
  const int bid = blockIdx.x;
  const int swz = (bid & 7) * cpx + (bid >> 3);
  const int mt  = swz / NT;
  const int nt  = swz - mt * NT;

  const int tid  = threadIdx.x;
  const int lane = tid & 63;
  const int wid  = tid >> 6;      // 8 waves: 2 (M) x 4 (N)
  const int wr   = wid >> 2;      // 0..1 -> 128 rows each
  const int wc   = wid & 3;       // 0..3 -> 64 cols each

  // ---- staging: linear LDS dest, pre-swizzled global source ----
  const int p_row   = tid >> 3;                  // 0..63 (row within 64-row chunk)
  const int l_chunk = (tid & 7) ^ (p_row & 7);   // inverse-swizzled 16B chunk
  const unsigned short* gA = A + (size_t)(mt * BM + p_row) * IN_F + l_chunk * 8;
  const unsigned short* gB = B + (size_t)(nt * BM + p_row) * IN_F + l_chunk * 8;
  unsigned short* ldsw = lds + tid * 8;          // linear dest, +16B/thread

#define STAGE_A(p, c, kk) gld16(gA + (size_t)(64 * (c)) * IN_F + (kk), \
                                ldsw + (p) * 32768 + (c) * 4096)
#define STAGE_B(p, c, kk) gld16(gB + (size_t)(64 * (c)) * IN_F + (kk), \
                                ldsw + (p) * 32768 + 16384 + (c) * 4096)

  // ---- fragment read addressing (swizzled) ----
  const int fr   = lane & 15;
  const int kq   = lane >> 4;                    // 0..3 (16B chunk within 32-elem k-step)
  const int axor = lane & 7;                     // row&7 == lane&7 (16-aligned row bases)
  const int c0   = ((kq) ^ axor) * 8;            // ushort col offset, k-step 0
  const int c1   = ((4 + kq) ^ axor) * 8;        // k-step 1
#define RD(base, row) /* two frags per call via c0/c1 at call site */
#define RDF(base, row, cs) (*reinterpret_cast<const bf16x8*>((base) + (size_t)(row) * 64 + (cs)))

  f32x4 acc[8][4] = {};
  bf16x8 a[4][2], b[4][2];

#define MFMA_Q(mh, nh) do {                                                        \
    __builtin_amdgcn_s_setprio(1);                                                 \
    _Pragma("unroll") for (int mm = 0; mm < 4; ++mm)                               \
      _Pragma("unroll") for (int nn = 0; nn < 2; ++nn) {                           \
        acc[(mh)*4+mm][(nh)*2+nn] = __builtin_amdgcn_mfma_f32_16x16x32_bf16(       \
            a[mm][0], b[(nh)*2+nn][0], acc[(mh)*4+mm][(nh)*2+nn], 0, 0, 0);        \
        acc[(mh)*4+mm][(nh)*2+nn] = __builtin_amdgcn_mfma_f32_16x16x32_bf16(       \
            a[mm][1], b[(nh)*2+nn][1], acc[(mh)*4+mm][(nh)*2+nn], 0, 0, 0);        \
      }                                                                            \
    __builtin_amdgcn_s_setprio(0);                                                 \
  } while (0)

  // ---- prologue: tile0 (A+B) + tile1 (A); allow tile1-A (4 loads) in flight ----
  STAGE_A(0, 0, 0); STAGE_A(0, 1, 0); STAGE_A(0, 2, 0); STAGE_A(0, 3, 0);
  STAGE_B(0, 0, 0); STAGE_B(0, 1, 0); STAGE_B(0, 2, 0); STAGE_B(0, 3, 0);
  STAGE_A(1, 0, BK); STAGE_A(1, 1, BK); STAGE_A(1, 2, BK); STAGE_A(1, 3, BK);
  asm volatile("s_waitcnt vmcnt(4)" ::: "memory");
  __builtin_amdgcn_s_barrier();
  asm volatile("" ::: "memory");

  for (int t = 0; t < NTILE_K; ++t) {
    const int p = t & 1, q = p ^ 1;
    const unsigned short* bufA = lds + p * 32768;
    const unsigned short* bufB = bufA + 16384;
    const int k1 = (t + 1 < NTILE_K ? t + 1 : 0) * BK;                       // wrap: harmless
    const int k2 = (t + 2 < NTILE_K ? t + 2 : t + 2 - NTILE_K) * BK;

    // ---- P1: read a(mh=0) + b(all); stage B(t+1) half0 ----
#pragma unroll
    for (int m = 0; m < 4; ++m) {
      const int r = wr * 128 + m * 16 + fr;
      a[m][0] = RDF(bufA, r, c0); a[m][1] = RDF(bufA, r, c1);
    }
#pragma unroll
    for (int n = 0; n < 4; ++n) {
      const int r = wc * 64 + n * 16 + fr;
      b[n][0] = RDF(bufB, r, c0); b[n][1] = RDF(bufB, r, c1);
    }
    STAGE_B(q, 0, k1); STAGE_B(q, 1, k1);
    BAR();
    MFMA_Q(0, 0);
    BAR();

    // ---- P2: stage B(t+1) half1 ----
    STAGE_B(q, 2, k1); STAGE_B(q, 3, k1);
    BAR();
    MFMA_Q(0, 1);
    BAR();

    // ---- P3: read a(mh=1) ----
#pragma unroll
    for (int m = 0; m < 4; ++m) {
      const int r = wr * 128 + 64 + m * 16 + fr;
      a[m][0] = RDF(bufA, r, c0); a[m][1] = RDF(bufA, r, c1);
    }
    BAR();
    MFMA_Q(1, 1);
    BAR();

    // ---- P4: stage A(t+2) (into buf p; its reads ended at P3); counted wait ----
    STAGE_A(p, 0, k2); STAGE_A(p, 1, k2); STAGE_A(p, 2, k2); STAGE_A(p, 3, k2);
    asm volatile("s_waitcnt vmcnt(4)" ::: "memory");  // tile t+1 fully resident; A(t+2) in flight
    BAR();
    MFMA_Q(1, 0);
    BAR();
  }

  // ---- epilogue: C write. frag m -> row offset (m>>2)*64 + (m&3)*16 ----
  const int col  = nt * BN + wc * 64 + fr;
  const int row0 = mt * BM + wr * 128 + (lane >> 4) * 4;
#pragma unroll
  for (int m = 0; m < 8; ++m) {
    const int ro = (m >> 2) * 64 + (m & 3) * 16;
#pragma unroll
    for (int n = 0; n < 4; ++n) {
      float* cp = C + (size_t)(row0 + ro) * OUT_F + (col + n * 16);
#pragma unroll
      for (int r = 0; r < 4; ++r) cp[(size_t)r * OUT_F] = acc[m][n][r];
    }
  }
}

extern "C" void kernel_launch(void* const* d_in, const int* in_sizes, int n_in,
                              void* d_out, int out_size, void* d_ws, size_t ws_size,
                              hipStream_t stream) {
  const float* x = (const float*)d_in[0];
  const int*   w = (const int*)d_in[1];
  const float* s = (const float*)d_in[2];
  float*     out = (float*)d_out;

  unsigned short* wb = (unsigned short*)d_ws;             // bf16 W  [OUT_F][IN_F]
  unsigned short* xb = wb + (size_t)OUT_F * IN_F;         // bf16 x  [M_ROWS][IN_F]

  dequant_q40<<<dim3(2048), dim3(256), 0, stream>>>(w, s, wb);
  cvt_x<<<dim3(2048), dim3(256), 0, stream>>>(x, xb);
  gemm_bt<<<dim3((M_ROWS / BM) * (OUT_F / BN)), dim3(512), 0, stream>>>(xb, wb, out);
}